// Round 6
// baseline (160.464 us; speedup 1.0000x reference)
//
#include <hip/hip_runtime.h>
#include <math.h>

#define LQ 1024
#define BZ 8
#define D  512
#define NH 8
#define DH 64
#define IOU_THR 0.2f
#define COS_THR 0.2f
#define NEG (-1e30f)
#define FIXCAP 16384

typedef short bf16x8 __attribute__((ext_vector_type(8)));
typedef float f32x4  __attribute__((ext_vector_type(4)));

#define MFMA16(a, b, cacc) __builtin_amdgcn_mfma_f32_16x16x32_bf16(a, b, cacc, 0, 0, 0)

__device__ inline unsigned short f2bf(float x) {
    union { float f; unsigned int u; } v; v.f = x;
    unsigned int r = v.u + 0x7FFF + ((v.u >> 16) & 1);
    return (unsigned short)(r >> 16);
}

// async global->LDS, 16B per lane. LDS base wave-uniform; HW adds lane*16.
__device__ __forceinline__ void gll16(const void* g, void* ldsbase) {
    __builtin_amdgcn_global_load_lds(
        (const __attribute__((address_space(1))) unsigned int*)g,
        (__attribute__((address_space(3))) unsigned int*)ldsbase, 16, 0, 0);
}

// ---------------------------------------------------------------------------
// Kernel 1: prep (query -> hi bf16, rnorm) + Wq/Wk/Wv -> bf16, fused by
// block range. h fp32 copy is GONE: h[b][i][:] == query[i][b][:] (contiguous).
// Blocks 0..2047: 4 rows each (1 wave/row, shuffle reduce, no LDS).
// Blocks 2048..2815: weight conversion.
// ---------------------------------------------------------------------------
__global__ __launch_bounds__(256) void prep_kernel(const float* __restrict__ query,
                                                   const float* __restrict__ Wq,
                                                   const float* __restrict__ Wk,
                                                   const float* __restrict__ Wv,
                                                   unsigned short* __restrict__ hi,
                                                   unsigned short* __restrict__ Wb,
                                                   float* __restrict__ rnorm) {
    int blk = blockIdx.x, tid = threadIdx.x;
    if (blk < 2048) {
        int w = tid >> 6, lane = tid & 63;
        int row = blk * 4 + w;                  // = b*LQ + i
        int b = row >> 10, i = row & 1023;
        const float* src = query + ((size_t)i * BZ + b) * D + lane * 8;
        float4 v0 = *(const float4*)src;
        float4 v1 = *(const float4*)(src + 4);
        uint4 pk;
        pk.x = (unsigned)f2bf(v0.x) | ((unsigned)f2bf(v0.y) << 16);
        pk.y = (unsigned)f2bf(v0.z) | ((unsigned)f2bf(v0.w) << 16);
        pk.z = (unsigned)f2bf(v1.x) | ((unsigned)f2bf(v1.y) << 16);
        pk.w = (unsigned)f2bf(v1.z) | ((unsigned)f2bf(v1.w) << 16);
        *(uint4*)(hi + (size_t)row * D + lane * 8) = pk;
        float ss = v0.x * v0.x + v0.y * v0.y + v0.z * v0.z + v0.w * v0.w
                 + v1.x * v1.x + v1.y * v1.y + v1.z * v1.z + v1.w * v1.w;
        #pragma unroll
        for (int s = 1; s < 64; s <<= 1) ss += __shfl_xor(ss, s);
        if (lane == 0) rnorm[row] = 1.0f / fmaxf(sqrtf(ss), 1e-8f);
    } else {
        int t = (blk - 2048) * 256 + tid;
        int mat = t >> 16;
        int off = (t & 65535) * 4;
        const float* src = (mat == 0) ? Wq : (mat == 1) ? Wk : Wv;
        float4 v = *(const float4*)(src + off);
        uint2 p;
        p.x = (unsigned)f2bf(v.x) | ((unsigned)f2bf(v.y) << 16);
        p.y = (unsigned)f2bf(v.z) | ((unsigned)f2bf(v.w) << 16);
        *(uint2*)(Wb + (size_t)mat * D * D + off) = p;
    }
}

// ---------------------------------------------------------------------------
// Kernel 2: fused mask + QKV GEMMs (no mutual dependency -> one dispatch).
// Blocks 0..767: QKV (z = blk/256). Blocks 768..1279: mask (b,it,jt).
// Both: 128x128 tile, BK=64, XOR-swizzled gll16 staging.
// ---------------------------------------------------------------------------
__global__ __launch_bounds__(256) void gemm_kernel(const unsigned short* __restrict__ hi,
                                                   const unsigned short* __restrict__ Wb,
                                                   const float* __restrict__ rnorm,
                                                   const float* __restrict__ segments,
                                                   const float* __restrict__ bq,
                                                   const float* __restrict__ bk,
                                                   const float* __restrict__ bv,
                                                   unsigned char* __restrict__ mask,
                                                   unsigned char* __restrict__ summ,
                                                   int* __restrict__ fix_cnt,
                                                   unsigned int* __restrict__ fix_list,
                                                   unsigned short* __restrict__ Qb,
                                                   unsigned short* __restrict__ Kb,
                                                   unsigned short* __restrict__ Vt) {
    __shared__ short As[128 * 64], Bs[128 * 64];   // 16 KB each
    __shared__ float4 iSE[128], jSE[128];          // mask path: (s, e, l, rnorm)
    __shared__ int summ_lds[8][2];
    int blk = blockIdx.x, tid = threadIdx.x, w = tid >> 6, lane = tid & 63;
    int c = lane & 15, q4 = lane >> 4;
    int wr = w >> 1, wc = w & 1;

    bool is_qkv = blk < 768;
    const char *Asrc, *Bsrc;
    int b = 0, i0 = 0, j0 = 0, z = 0, m0 = 0, n0 = 0;
    if (is_qkv) {
        z = blk >> 8; int rem = blk & 255;
        m0 = (rem >> 2) * 128; n0 = (rem & 3) * 128;
        Asrc = (const char*)(hi + (size_t)m0 * D);
        Bsrc = (const char*)(Wb + (size_t)z * D * D + (size_t)n0 * D);
    } else {
        int id2 = blk - 768;
        b = id2 >> 6; i0 = ((id2 >> 3) & 7) * 128; j0 = (id2 & 7) * 128;
        Asrc = (const char*)(hi + ((size_t)b * LQ + i0) * D);
        Bsrc = (const char*)(hi + ((size_t)b * LQ + j0) * D);
        if (tid < 16) summ_lds[tid >> 1][tid & 1] = 0;
    }

    // staging: chunk n (1 KB) = rows 8n..8n+7; lane L -> row 8n+(L>>3),
    // global 16B sub-chunk (L&7)^((L>>3)&7) (XOR swizzle)
    int rgrp = lane >> 3;
    int qg   = (lane & 7) ^ (rgrp & 7);
    size_t lgoff = (size_t)rgrp * 1024 + (size_t)qg * 16;
    int swz = c & 7;

    f32x4 acc[4][4] = {};
    for (int k0 = 0; k0 < D; k0 += 64) {
        size_t kb = (size_t)k0 * 2;
        #pragma unroll
        for (int m = 0; m < 4; m++) {
            int n = 4 * w + m;
            gll16(Asrc + kb + (size_t)n * 8192 + lgoff, (char*)As + n * 1024);
            gll16(Bsrc + kb + (size_t)n * 8192 + lgoff, (char*)Bs + n * 1024);
        }
        __syncthreads();
        #pragma unroll
        for (int s = 0; s < 2; s++) {
            bf16x8 af[4], bf[4];
            #pragma unroll
            for (int f = 0; f < 4; f++) {
                af[f] = *(const bf16x8*)&As[(wr * 64 + f * 16 + c) * 64 + ((s * 4 + q4) ^ swz) * 8];
                bf[f] = *(const bf16x8*)&Bs[(wc * 64 + f * 16 + c) * 64 + ((s * 4 + q4) ^ swz) * 8];
            }
            #pragma unroll
            for (int fr = 0; fr < 4; fr++)
                #pragma unroll
                for (int fc = 0; fc < 4; fc++)
                    acc[fr][fc] = MFMA16(af[fr], bf[fc], acc[fr][fc]);
        }
        __syncthreads();
    }

    if (is_qkv) {
        const float* bias = (z == 0) ? bq : (z == 1) ? bk : bv;
        #pragma unroll
        for (int fr = 0; fr < 4; fr++)
            #pragma unroll
            for (int r = 0; r < 4; r++) {
                int m = m0 + wr * 64 + fr * 16 + q4 * 4 + r;
                int bb = m >> 10, i = m & 1023;
                #pragma unroll
                for (int fc = 0; fc < 4; fc++) {
                    int n = n0 + wc * 64 + fc * 16 + c;
                    unsigned short us = f2bf(acc[fr][fc][r] + bias[n]);
                    int hh = n >> 6, dh = n & 63;
                    size_t bh = (size_t)bb * NH + hh;
                    if (z == 2)
                        Vt[(bh * DH + dh) * LQ + i] = us;
                    else {
                        unsigned short* dst = (z == 0) ? Qb : Kb;
                        dst[(bh * LQ + i) * DH + dh] = us;
                    }
                }
            }
    } else {
        // stage segment geometry + rnorm (coalesced, once per block)
        const float2* seg2 = (const float2*)(segments + (size_t)b * LQ * 2);
        const float* rn = rnorm + b * LQ;
        if (tid < 128) {
            float2 cl = seg2[i0 + tid];
            iSE[tid] = make_float4(cl.x - cl.y * 0.5f, cl.x + cl.y * 0.5f, cl.y, rn[i0 + tid]);
        } else {
            float2 cl = seg2[j0 + tid - 128];
            jSE[tid - 128] = make_float4(cl.x - cl.y * 0.5f, cl.x + cl.y * 0.5f, cl.y, rn[j0 + tid - 128]);
        }
        __syncthreads();

        unsigned char* mbase = mask + ((size_t)b << 20);
        #pragma unroll
        for (int fr = 0; fr < 4; fr++) {
            int anyun = 0;
            #pragma unroll
            for (int r = 0; r < 4; r++) {
                int il = wr * 64 + fr * 16 + q4 * 4 + r;
                int i = i0 + il;
                float4 I = iSE[il];
                #pragma unroll
                for (int fc = 0; fc < 4; fc++) {
                    int jl = wc * 64 + fc * 16 + c;
                    int j = j0 + jl;
                    float4 J = jSE[jl];
                    float cosv = acc[fr][fc][r] * I.w * J.w;
                    if (fabsf(cosv - COS_THR) < 1.5e-3f) {     // defer exact recompute
                        int idx = atomicAdd(fix_cnt, 1);
                        if (idx < FIXCAP)
                            fix_list[idx] = ((unsigned int)b << 20) | ((unsigned int)i << 10) | j;
                    }
                    float inter = fmaxf(fminf(I.y, J.y) - fmaxf(I.x, J.x), 0.0f);
                    float uni   = I.z + J.z - inter;
                    float iou   = inter / uni;
                    bool adj = ((iou <= IOU_THR) || (i == j)) && (cosv > COS_THR);
                    mbase[(size_t)i * LQ + j] = adj ? 0 : 1;   // 1 = masked
                    anyun |= adj ? 1 : 0;
                }
            }
            if (anyun) atomicOr(&summ_lds[wr * 4 + fr][wc], 1);
        }
        __syncthreads();
        if (tid < 16) {
            int lit = tid >> 1, ljt = tid & 1;
            summ[((size_t)b * 64 + (i0 >> 4) + lit) * 16 + (j0 >> 6) + ljt] =
                summ_lds[lit][ljt] ? 1 : 0;
        }
    }
}

// ---------------------------------------------------------------------------
// Kernel 3: fixup — one wave per flagged element; cooperative fp64 dot over
// query rows (h[b][i][:] == query[i][b][:], contiguous). Stale summ=1 is safe
// (online softmax self-heals fully-masked tiles).
// ---------------------------------------------------------------------------
__global__ __launch_bounds__(64) void fixup_kernel(const float* __restrict__ query,
                                                   const float* __restrict__ rnorm,
                                                   const float* __restrict__ segments,
                                                   const int* __restrict__ fix_cnt,
                                                   const unsigned int* __restrict__ fix_list,
                                                   unsigned char* __restrict__ mask,
                                                   unsigned char* __restrict__ summ) {
    int cnt = *fix_cnt; if (cnt > FIXCAP) cnt = FIXCAP;
    int lane = threadIdx.x;
    for (int e = blockIdx.x; e < cnt; e += gridDim.x) {
        unsigned int pk = fix_list[e];
        int b = pk >> 20, i = (pk >> 10) & 1023, j = pk & 1023;
        const float* hri = query + ((size_t)i * BZ + b) * D;
        const float* hrj = query + ((size_t)j * BZ + b) * D;
        double dd = 0.0;
        #pragma unroll
        for (int k = 0; k < D / 64; k++)
            dd += (double)hri[k * 64 + lane] * (double)hrj[k * 64 + lane];
        #pragma unroll
        for (int s = 1; s < 64; s <<= 1) dd += __shfl_xor(dd, s);
        if (lane == 0) {
            float rni = rnorm[b * LQ + i], rnj = rnorm[b * LQ + j];
            float cosv = (float)(dd * (double)rni * (double)rnj);
            const float* seg = segments + (size_t)b * LQ * 2;
            float ci = seg[i * 2], li = seg[i * 2 + 1];
            float cj = seg[j * 2], lj = seg[j * 2 + 1];
            float si = ci - li * 0.5f, ei = ci + li * 0.5f;
            float sj = cj - lj * 0.5f, ej = cj + lj * 0.5f;
            float inter = fmaxf(fminf(ei, ej) - fmaxf(si, sj), 0.0f);
            float iou = inter / (li + lj - inter);
            bool adj = ((iou <= IOU_THR) || (i == j)) && (cosv > COS_THR);
            mask[((size_t)b * LQ + i) * LQ + j] = adj ? 0 : 1;
            if (adj) summ[((size_t)b * 64 + (i >> 4)) * 16 + (j >> 6)] = 1;
        }
    }
}

// ---------------------------------------------------------------------------
// Kernel 4: flash MFMA attention, summary-driven tile skipping; residual read
// directly from query (out[i][b][col] = O/l + query[i][b][col]).
// ---------------------------------------------------------------------------
__global__ __launch_bounds__(256) void attn_kernel(const unsigned short* __restrict__ Qb,
                                                   const unsigned short* __restrict__ Kb,
                                                   const unsigned short* __restrict__ Vt,
                                                   const unsigned char* __restrict__ mask,
                                                   const unsigned char* __restrict__ summ,
                                                   const float* __restrict__ query,
                                                   float* __restrict__ out) {
    int tid = threadIdx.x;
    int w = tid >> 6, lane = tid & 63;
    int c = lane & 15, q4 = lane >> 4;
    int hh = blockIdx.y, b = blockIdx.z;
    int i0 = blockIdx.x * 64 + w * 16;
    size_t bh = (size_t)b * NH + hh;

    __shared__ unsigned short p_lds[4][16][72];

    const unsigned short* Qrow = Qb + (bh * LQ + i0 + c) * DH;
    bf16x8 qa0 = *(const bf16x8*)(Qrow + q4 * 8);
    bf16x8 qa1 = *(const bf16x8*)(Qrow + 32 + q4 * 8);

    f32x4 O[4] = {};
    float m_r[4] = {NEG, NEG, NEG, NEG};
    float l_r[4] = {0.f, 0.f, 0.f, 0.f};

    const unsigned short* Kbase = Kb + bh * LQ * DH;
    const unsigned short* Vbase = Vt + bh * DH * LQ;
    const unsigned char*  mbase = mask + ((size_t)b * LQ + i0) * LQ;
    const unsigned char*  srow  = summ + ((size_t)b * 64 + (i0 >> 4)) * 16;

    for (int jt = 0; jt < 16; jt++) {
        if (!srow[jt]) continue;           // fully-masked tile: contributes nothing
        int j0 = jt * 64;
        f32x4 S[4] = {};
        #pragma unroll
        for (int cb = 0; cb < 4; cb++) {
            const unsigned short* krow = Kbase + (size_t)(j0 + cb * 16 + c) * DH;
            bf16x8 kf0 = *(const bf16x8*)(krow + q4 * 8);
            bf16x8 kf1 = *(const bf16x8*)(krow + 32 + q4 * 8);
            S[cb] = MFMA16(qa0, kf0, S[cb]);
            S[cb] = MFMA16(qa1, kf1, S[cb]);
        }
        float p[4][4];
        float tmax[4] = {NEG, NEG, NEG, NEG};
        #pragma unroll
        for (int cb = 0; cb < 4; cb++)
            #pragma unroll
            for (int r = 0; r < 4; r++) {
                float sc = S[cb][r] * 0.125f;
                unsigned char mm = mbase[(size_t)(q4 * 4 + r) * LQ + j0 + cb * 16 + c];
                sc = mm ? NEG : sc;
                p[cb][r] = sc;
                tmax[r] = fmaxf(tmax[r], sc);
            }
        #pragma unroll
        for (int r = 0; r < 4; r++) {
            float v = tmax[r];
            v = fmaxf(v, __shfl_xor(v, 1));
            v = fmaxf(v, __shfl_xor(v, 2));
            v = fmaxf(v, __shfl_xor(v, 4));
            v = fmaxf(v, __shfl_xor(v, 8));
            tmax[r] = v;
        }
        float rsum[4];
        #pragma unroll
        for (int r = 0; r < 4; r++) {
            float mn = fmaxf(m_r[r], tmax[r]);
            float alpha = __expf(m_r[r] - mn);
            m_r[r] = mn;
            l_r[r] *= alpha;
            #pragma unroll
            for (int cb2 = 0; cb2 < 4; cb2++) O[cb2][r] *= alpha;
            float s0 = 0.f;
            #pragma unroll
            for (int cb = 0; cb < 4; cb++) {
                float e = __expf(p[cb][r] - mn);
                p[cb][r] = e;
                s0 += e;
            }
            rsum[r] = s0;
        }
        #pragma unroll
        for (int r = 0; r < 4; r++) {
            float v = rsum[r];
            v += __shfl_xor(v, 1);
            v += __shfl_xor(v, 2);
            v += __shfl_xor(v, 4);
            v += __shfl_xor(v, 8);
            l_r[r] += v;
        }
        #pragma unroll
        for (int cb = 0; cb < 4; cb++)
            #pragma unroll
            for (int r = 0; r < 4; r++)
                p_lds[w][q4 * 4 + r][cb * 16 + c] = f2bf(p[cb][r]);
        // per-wave LDS: wave-internal lgkmcnt ordering suffices, no barrier
        #pragma unroll
        for (int s = 0; s < 2; s++) {
            bf16x8 pf = *(const bf16x8*)&p_lds[w][c][s * 32 + q4 * 8];
            #pragma unroll
            for (int cb = 0; cb < 4; cb++) {
                bf16x8 vf = *(const bf16x8*)(Vbase + (size_t)(cb * 16 + c) * LQ + j0 + s * 32 + q4 * 8);
                O[cb] = MFMA16(pf, vf, O[cb]);
            }
        }
    }
    #pragma unroll
    for (int r = 0; r < 4; r++) {
        int i = i0 + q4 * 4 + r;
        float inv = 1.0f / l_r[r];
        #pragma unroll
        for (int cb = 0; cb < 4; cb++) {
            int col = hh * 64 + cb * 16 + c;
            size_t oidx = ((size_t)i * BZ + b) * D + col;
            out[oidx] = O[cb][r] * inv + query[oidx];
        }
    }
}

// ---------------------------------------------------------------------------
extern "C" void kernel_launch(void* const* d_in, const int* in_sizes, int n_in,
                              void* d_out, int out_size, void* d_ws, size_t ws_size,
                              hipStream_t stream) {
    const float* query    = (const float*)d_in[0];
    const float* segments = (const float*)d_in[1];
    const float* Wq = (const float*)d_in[2];
    const float* bq = (const float*)d_in[3];
    const float* Wk = (const float*)d_in[4];
    const float* bk = (const float*)d_in[5];
    const float* Wv = (const float*)d_in[6];
    const float* bv = (const float*)d_in[7];
    float* out = (float*)d_out;

    const size_t NTOK = (size_t)BZ * LQ;
    char* ws = (char*)d_ws;
    unsigned short* hbuf  = (unsigned short*)ws;   ws += NTOK * D * 2;          // 8 MB
    unsigned short* Qb    = (unsigned short*)ws;   ws += NTOK * D * 2;          // 8 MB
    unsigned short* Kb    = (unsigned short*)ws;   ws += NTOK * D * 2;          // 8 MB
    unsigned short* Vt    = (unsigned short*)ws;   ws += NTOK * D * 2;          // 8 MB
    unsigned short* Wb    = (unsigned short*)ws;   ws += (size_t)3 * D * D * 2; // 1.5 MB
    float*          rnorm = (float*)ws;            ws += NTOK * 4;              // 32 KB
    unsigned char*  mask  = (unsigned char*)ws;    ws += (size_t)BZ * LQ * LQ;  // 8 MB
    unsigned char*  summ  = (unsigned char*)ws;    ws += 8192;                  // 8 KB
    int*            fix_cnt = (int*)ws;            ws += 64;
    unsigned int*   fix_list = (unsigned int*)ws;  /* 64 KB */

    hipMemsetAsync(fix_cnt, 0, 64, stream);
    prep_kernel<<<2816, 256, 0, stream>>>(query, Wq, Wk, Wv, hbuf, Wb, rnorm);
    gemm_kernel<<<1280, 256, 0, stream>>>(hbuf, Wb, rnorm, segments, bq, bk, bv,
                                          mask, summ, fix_cnt, fix_list, Qb, Kb, Vt);
    fixup_kernel<<<64, 64, 0, stream>>>(query, rnorm, segments, fix_cnt, fix_list, mask, summ);
    attn_kernel<<<dim3(LQ / 64, NH, BZ), 256, 0, stream>>>(Qb, Kb, Vt, mask, summ, query, out);
}

// Round 7
// 160.179 us; speedup vs baseline: 1.0018x; 1.0018x over previous
//
#include <hip/hip_runtime.h>
#include <math.h>

#define LQ 1024
#define BZ 8
#define D  512
#define NH 8
#define DH 64
#define IOU_THR 0.2f
#define COS_THR 0.2f
#define NEG (-1e30f)
#define FIXCAP 16384

typedef short bf16x8 __attribute__((ext_vector_type(8)));
typedef float f32x4  __attribute__((ext_vector_type(4)));

#define MFMA16(a, b, cacc) __builtin_amdgcn_mfma_f32_16x16x32_bf16(a, b, cacc, 0, 0, 0)

__device__ inline unsigned short f2bf(float x) {
    union { float f; unsigned int u; } v; v.f = x;
    unsigned int r = v.u + 0x7FFF + ((v.u >> 16) & 1);
    return (unsigned short)(r >> 16);
}

// async global->LDS, 16B per lane. LDS base wave-uniform; HW adds lane*16.
__device__ __forceinline__ void gll16(const void* g, void* ldsbase) {
    __builtin_amdgcn_global_load_lds(
        (const __attribute__((address_space(1))) unsigned int*)g,
        (__attribute__((address_space(3))) unsigned int*)ldsbase, 16, 0, 0);
}

// ---------------------------------------------------------------------------
// Kernel 1: prep (query -> hi bf16, rnorm) + Wq/Wk/Wv -> bf16, fused.
// ---------------------------------------------------------------------------
__global__ __launch_bounds__(256) void prep_kernel(const float* __restrict__ query,
                                                   const float* __restrict__ Wq,
                                                   const float* __restrict__ Wk,
                                                   const float* __restrict__ Wv,
                                                   unsigned short* __restrict__ hi,
                                                   unsigned short* __restrict__ Wb,
                                                   float* __restrict__ rnorm) {
    int blk = blockIdx.x, tid = threadIdx.x;
    if (blk < 2048) {
        int w = tid >> 6, lane = tid & 63;
        int row = blk * 4 + w;                  // = b*LQ + i
        int b = row >> 10, i = row & 1023;
        const float* src = query + ((size_t)i * BZ + b) * D + lane * 8;
        float4 v0 = *(const float4*)src;
        float4 v1 = *(const float4*)(src + 4);
        uint4 pk;
        pk.x = (unsigned)f2bf(v0.x) | ((unsigned)f2bf(v0.y) << 16);
        pk.y = (unsigned)f2bf(v0.z) | ((unsigned)f2bf(v0.w) << 16);
        pk.z = (unsigned)f2bf(v1.x) | ((unsigned)f2bf(v1.y) << 16);
        pk.w = (unsigned)f2bf(v1.z) | ((unsigned)f2bf(v1.w) << 16);
        *(uint4*)(hi + (size_t)row * D + lane * 8) = pk;
        float ss = v0.x * v0.x + v0.y * v0.y + v0.z * v0.z + v0.w * v0.w
                 + v1.x * v1.x + v1.y * v1.y + v1.z * v1.z + v1.w * v1.w;
        #pragma unroll
        for (int s = 1; s < 64; s <<= 1) ss += __shfl_xor(ss, s);
        if (lane == 0) rnorm[row] = 1.0f / fmaxf(sqrtf(ss), 1e-8f);
    } else {
        int t = (blk - 2048) * 256 + tid;
        int mat = t >> 16;
        int off = (t & 65535) * 4;
        const float* src = (mat == 0) ? Wq : (mat == 1) ? Wk : Wv;
        float4 v = *(const float4*)(src + off);
        uint2 p;
        p.x = (unsigned)f2bf(v.x) | ((unsigned)f2bf(v.y) << 16);
        p.y = (unsigned)f2bf(v.z) | ((unsigned)f2bf(v.w) << 16);
        *(uint2*)(Wb + (size_t)mat * D * D + off) = p;
    }
}

// ---------------------------------------------------------------------------
// Kernel 2: fused QKV + symmetric mask GEMMs.
// Blocks 0..767: QKV. Blocks 768..1055: mask upper-triangular tiles only
// (cos/iou/diag are all symmetric; off-diag blocks also write the transposed
// tile + transposed summary). 128x128 tile, BK=64, XOR-swizzled staging.
// ---------------------------------------------------------------------------
__global__ __launch_bounds__(256) void gemm_kernel(const unsigned short* __restrict__ hi,
                                                   const unsigned short* __restrict__ Wb,
                                                   const float* __restrict__ rnorm,
                                                   const float* __restrict__ segments,
                                                   const float* __restrict__ bq,
                                                   const float* __restrict__ bk,
                                                   const float* __restrict__ bv,
                                                   unsigned char* __restrict__ mask,
                                                   unsigned char* __restrict__ summ,
                                                   int* __restrict__ fix_cnt,
                                                   unsigned int* __restrict__ fix_list,
                                                   unsigned short* __restrict__ Qb,
                                                   unsigned short* __restrict__ Kb,
                                                   unsigned short* __restrict__ Vt) {
    __shared__ short As[128 * 64], Bs[128 * 64];   // 16 KB each
    __shared__ float4 iSE[128], jSE[128];          // mask path: (s, e, l, rnorm)
    __shared__ int summ_lds[8][2], summ_t_lds[8][2];
    int blk = blockIdx.x, tid = threadIdx.x, w = tid >> 6, lane = tid & 63;
    int c = lane & 15, q4 = lane >> 4;
    int wr = w >> 1, wc = w & 1;

    bool is_qkv = blk < 768;
    const char *Asrc, *Bsrc;
    int b = 0, i0 = 0, j0 = 0, z = 0, m0 = 0, n0 = 0;
    if (is_qkv) {
        z = blk >> 8; int rem = blk & 255;
        m0 = (rem >> 2) * 128; n0 = (rem & 3) * 128;
        Asrc = (const char*)(hi + (size_t)m0 * D);
        Bsrc = (const char*)(Wb + (size_t)z * D * D + (size_t)n0 * D);
    } else {
        int id2 = blk - 768;           // 0..287
        b = id2 / 36;
        int t = id2 - b * 36;          // triangular index, it<=jt over 8x8
        int it = 0;
        while (t >= 8 - it) { t -= 8 - it; it++; }
        int jt = it + t;
        i0 = it * 128; j0 = jt * 128;
        Asrc = (const char*)(hi + ((size_t)b * LQ + i0) * D);
        Bsrc = (const char*)(hi + ((size_t)b * LQ + j0) * D);
        if (tid < 16) {
            summ_lds[tid >> 1][tid & 1] = 0;
            summ_t_lds[tid >> 1][tid & 1] = 0;
        }
    }

    // staging: chunk n (1 KB) = rows 8n..8n+7; lane L -> row 8n+(L>>3),
    // global 16B sub-chunk (L&7)^((L>>3)&7) (XOR swizzle)
    int rgrp = lane >> 3;
    int qg   = (lane & 7) ^ (rgrp & 7);
    size_t lgoff = (size_t)rgrp * 1024 + (size_t)qg * 16;
    int swz = c & 7;

    f32x4 acc[4][4] = {};
    for (int k0 = 0; k0 < D; k0 += 64) {
        size_t kb = (size_t)k0 * 2;
        #pragma unroll
        for (int m = 0; m < 4; m++) {
            int n = 4 * w + m;
            gll16(Asrc + kb + (size_t)n * 8192 + lgoff, (char*)As + n * 1024);
            gll16(Bsrc + kb + (size_t)n * 8192 + lgoff, (char*)Bs + n * 1024);
        }
        __syncthreads();
        #pragma unroll
        for (int s = 0; s < 2; s++) {
            bf16x8 af[4], bf[4];
            #pragma unroll
            for (int f = 0; f < 4; f++) {
                af[f] = *(const bf16x8*)&As[(wr * 64 + f * 16 + c) * 64 + ((s * 4 + q4) ^ swz) * 8];
                bf[f] = *(const bf16x8*)&Bs[(wc * 64 + f * 16 + c) * 64 + ((s * 4 + q4) ^ swz) * 8];
            }
            #pragma unroll
            for (int fr = 0; fr < 4; fr++)
                #pragma unroll
                for (int fc = 0; fc < 4; fc++)
                    acc[fr][fc] = MFMA16(af[fr], bf[fc], acc[fr][fc]);
        }
        __syncthreads();
    }

    if (is_qkv) {
        const float* bias = (z == 0) ? bq : (z == 1) ? bk : bv;
        #pragma unroll
        for (int fr = 0; fr < 4; fr++)
            #pragma unroll
            for (int r = 0; r < 4; r++) {
                int m = m0 + wr * 64 + fr * 16 + q4 * 4 + r;
                int bb = m >> 10, i = m & 1023;
                #pragma unroll
                for (int fc = 0; fc < 4; fc++) {
                    int n = n0 + wc * 64 + fc * 16 + c;
                    unsigned short us = f2bf(acc[fr][fc][r] + bias[n]);
                    int hh = n >> 6, dh = n & 63;
                    size_t bh = (size_t)bb * NH + hh;
                    if (z == 2)
                        Vt[(bh * DH + dh) * LQ + i] = us;
                    else {
                        unsigned short* dst = (z == 0) ? Qb : Kb;
                        dst[(bh * LQ + i) * DH + dh] = us;
                    }
                }
            }
    } else {
        // stage segment geometry + rnorm (coalesced, once per block)
        const float2* seg2 = (const float2*)(segments + (size_t)b * LQ * 2);
        const float* rn = rnorm + b * LQ;
        if (tid < 128) {
            float2 cl = seg2[i0 + tid];
            iSE[tid] = make_float4(cl.x - cl.y * 0.5f, cl.x + cl.y * 0.5f, cl.y, rn[i0 + tid]);
        } else {
            float2 cl = seg2[j0 + tid - 128];
            jSE[tid - 128] = make_float4(cl.x - cl.y * 0.5f, cl.x + cl.y * 0.5f, cl.y, rn[j0 + tid - 128]);
        }
        __syncthreads();

        bool offdiag = (i0 != j0);
        unsigned char* mbase = mask + ((size_t)b << 20);
        int anyT[4] = {0, 0, 0, 0};    // transposed summary, per fc
        #pragma unroll
        for (int fr = 0; fr < 4; fr++) {
            int anyun = 0;
            unsigned int tpack[4] = {0, 0, 0, 0};   // transposed bytes, packed over r
            #pragma unroll
            for (int r = 0; r < 4; r++) {
                int il = wr * 64 + fr * 16 + q4 * 4 + r;
                int i = i0 + il;
                float4 I = iSE[il];
                #pragma unroll
                for (int fc = 0; fc < 4; fc++) {
                    int jl = wc * 64 + fc * 16 + c;
                    int j = j0 + jl;
                    float4 J = jSE[jl];
                    float cosv = acc[fr][fc][r] * I.w * J.w;
                    if (fabsf(cosv - COS_THR) < 1.5e-3f) {     // defer exact recompute
                        int idx = atomicAdd(fix_cnt, 1);
                        if (idx < FIXCAP)
                            fix_list[idx] = ((unsigned int)b << 20) | ((unsigned int)i << 10) | j;
                    }
                    float inter = fmaxf(fminf(I.y, J.y) - fmaxf(I.x, J.x), 0.0f);
                    float uni   = I.z + J.z - inter;
                    float iou   = inter / uni;
                    bool adj = ((iou <= IOU_THR) || (i == j)) && (cosv > COS_THR);
                    mbase[(size_t)i * LQ + j] = adj ? 0 : 1;   // 1 = masked
                    tpack[fc] |= (adj ? 0u : 1u) << (8 * r);
                    anyun |= adj ? 1 : 0;
                    anyT[fc] |= adj ? 1 : 0;
                }
            }
            if (anyun) atomicOr(&summ_lds[wr * 4 + fr][wc], 1);
            if (offdiag) {
                int ibase = i0 + wr * 64 + fr * 16 + q4 * 4;   // 4-aligned
                #pragma unroll
                for (int fc = 0; fc < 4; fc++) {
                    int j = j0 + wc * 64 + fc * 16 + c;
                    *(unsigned int*)&mbase[(size_t)j * LQ + ibase] = tpack[fc];
                }
            }
        }
        if (offdiag) {
            #pragma unroll
            for (int fc = 0; fc < 4; fc++)
                if (anyT[fc]) atomicOr(&summ_t_lds[wc * 4 + fc][wr], 1);
        }
        __syncthreads();
        if (tid < 16) {
            int lit = tid >> 1, ljt = tid & 1;
            summ[((size_t)b * 64 + (i0 >> 4) + lit) * 16 + (j0 >> 6) + ljt] =
                summ_lds[lit][ljt] ? 1 : 0;
            if (offdiag)
                summ[((size_t)b * 64 + (j0 >> 4) + lit) * 16 + (i0 >> 6) + ljt] =
                    summ_t_lds[lit][ljt] ? 1 : 0;
        }
    }
}

// ---------------------------------------------------------------------------
// Kernel 3: fixup — one wave per flagged element; cooperative fp64 dot over
// query rows. Patches BOTH (i,j) and (j,i) (mask is symmetric). Stale summ=1
// is safe (online softmax self-heals fully-masked tiles).
// ---------------------------------------------------------------------------
__global__ __launch_bounds__(64) void fixup_kernel(const float* __restrict__ query,
                                                   const float* __restrict__ rnorm,
                                                   const float* __restrict__ segments,
                                                   const int* __restrict__ fix_cnt,
                                                   const unsigned int* __restrict__ fix_list,
                                                   unsigned char* __restrict__ mask,
                                                   unsigned char* __restrict__ summ) {
    int cnt = *fix_cnt; if (cnt > FIXCAP) cnt = FIXCAP;
    int lane = threadIdx.x;
    for (int e = blockIdx.x; e < cnt; e += gridDim.x) {
        unsigned int pk = fix_list[e];
        int b = pk >> 20, i = (pk >> 10) & 1023, j = pk & 1023;
        const float* hri = query + ((size_t)i * BZ + b) * D;
        const float* hrj = query + ((size_t)j * BZ + b) * D;
        double dd = 0.0;
        #pragma unroll
        for (int k = 0; k < D / 64; k++)
            dd += (double)hri[k * 64 + lane] * (double)hrj[k * 64 + lane];
        #pragma unroll
        for (int s = 1; s < 64; s <<= 1) dd += __shfl_xor(dd, s);
        if (lane == 0) {
            float rni = rnorm[b * LQ + i], rnj = rnorm[b * LQ + j];
            float cosv = (float)(dd * (double)rni * (double)rnj);
            const float* seg = segments + (size_t)b * LQ * 2;
            float ci = seg[i * 2], li = seg[i * 2 + 1];
            float cj = seg[j * 2], lj = seg[j * 2 + 1];
            float si = ci - li * 0.5f, ei = ci + li * 0.5f;
            float sj = cj - lj * 0.5f, ej = cj + lj * 0.5f;
            float inter = fmaxf(fminf(ei, ej) - fmaxf(si, sj), 0.0f);
            float iou = inter / (li + lj - inter);
            bool adj = ((iou <= IOU_THR) || (i == j)) && (cosv > COS_THR);
            unsigned char mv = adj ? 0 : 1;
            mask[((size_t)b * LQ + i) * LQ + j] = mv;
            mask[((size_t)b * LQ + j) * LQ + i] = mv;
            if (adj) {
                summ[((size_t)b * 64 + (i >> 4)) * 16 + (j >> 6)] = 1;
                summ[((size_t)b * 64 + (j >> 4)) * 16 + (i >> 6)] = 1;
            }
        }
    }
}

// ---------------------------------------------------------------------------
// Kernel 4: flash MFMA attention, summary-driven tile skipping; residual read
// directly from query (out[i][b][col] = O/l + query[i][b][col]).
// ---------------------------------------------------------------------------
__global__ __launch_bounds__(256) void attn_kernel(const unsigned short* __restrict__ Qb,
                                                   const unsigned short* __restrict__ Kb,
                                                   const unsigned short* __restrict__ Vt,
                                                   const unsigned char* __restrict__ mask,
                                                   const unsigned char* __restrict__ summ,
                                                   const float* __restrict__ query,
                                                   float* __restrict__ out) {
    int tid = threadIdx.x;
    int w = tid >> 6, lane = tid & 63;
    int c = lane & 15, q4 = lane >> 4;
    int hh = blockIdx.y, b = blockIdx.z;
    int i0 = blockIdx.x * 64 + w * 16;
    size_t bh = (size_t)b * NH + hh;

    __shared__ unsigned short p_lds[4][16][72];

    const unsigned short* Qrow = Qb + (bh * LQ + i0 + c) * DH;
    bf16x8 qa0 = *(const bf16x8*)(Qrow + q4 * 8);
    bf16x8 qa1 = *(const bf16x8*)(Qrow + 32 + q4 * 8);

    f32x4 O[4] = {};
    float m_r[4] = {NEG, NEG, NEG, NEG};
    float l_r[4] = {0.f, 0.f, 0.f, 0.f};

    const unsigned short* Kbase = Kb + bh * LQ * DH;
    const unsigned short* Vbase = Vt + bh * DH * LQ;
    const unsigned char*  mbase = mask + ((size_t)b * LQ + i0) * LQ;
    const unsigned char*  srow  = summ + ((size_t)b * 64 + (i0 >> 4)) * 16;

    for (int jt = 0; jt < 16; jt++) {
        if (!srow[jt]) continue;           // fully-masked tile: contributes nothing
        int j0 = jt * 64;
        f32x4 S[4] = {};
        #pragma unroll
        for (int cb = 0; cb < 4; cb++) {
            const unsigned short* krow = Kbase + (size_t)(j0 + cb * 16 + c) * DH;
            bf16x8 kf0 = *(const bf16x8*)(krow + q4 * 8);
            bf16x8 kf1 = *(const bf16x8*)(krow + 32 + q4 * 8);
            S[cb] = MFMA16(qa0, kf0, S[cb]);
            S[cb] = MFMA16(qa1, kf1, S[cb]);
        }
        float p[4][4];
        float tmax[4] = {NEG, NEG, NEG, NEG};
        #pragma unroll
        for (int cb = 0; cb < 4; cb++)
            #pragma unroll
            for (int r = 0; r < 4; r++) {
                float sc = S[cb][r] * 0.125f;
                unsigned char mm = mbase[(size_t)(q4 * 4 + r) * LQ + j0 + cb * 16 + c];
                sc = mm ? NEG : sc;
                p[cb][r] = sc;
                tmax[r] = fmaxf(tmax[r], sc);
            }
        #pragma unroll
        for (int r = 0; r < 4; r++) {
            float v = tmax[r];
            v = fmaxf(v, __shfl_xor(v, 1));
            v = fmaxf(v, __shfl_xor(v, 2));
            v = fmaxf(v, __shfl_xor(v, 4));
            v = fmaxf(v, __shfl_xor(v, 8));
            tmax[r] = v;
        }
        float rsum[4];
        #pragma unroll
        for (int r = 0; r < 4; r++) {
            float mn = fmaxf(m_r[r], tmax[r]);
            float alpha = __expf(m_r[r] - mn);
            m_r[r] = mn;
            l_r[r] *= alpha;
            #pragma unroll
            for (int cb2 = 0; cb2 < 4; cb2++) O[cb2][r] *= alpha;
            float s0 = 0.f;
            #pragma unroll
            for (int cb = 0; cb < 4; cb++) {
                float e = __expf(p[cb][r] - mn);
                p[cb][r] = e;
                s0 += e;
            }
            rsum[r] = s0;
        }
        #pragma unroll
        for (int r = 0; r < 4; r++) {
            float v = rsum[r];
            v += __shfl_xor(v, 1);
            v += __shfl_xor(v, 2);
            v += __shfl_xor(v, 4);
            v += __shfl_xor(v, 8);
            l_r[r] += v;
        }
        #pragma unroll
        for (int cb = 0; cb < 4; cb++)
            #pragma unroll
            for (int r = 0; r < 4; r++)
                p_lds[w][q4 * 4 + r][cb * 16 + c] = f2bf(p[cb][r]);
        // per-wave LDS: wave-internal lgkmcnt ordering suffices, no barrier
        #pragma unroll
        for (int s = 0; s < 2; s++) {
            bf16x8 pf = *(const bf16x8*)&p_lds[w][c][s * 32 + q4 * 8];
            #pragma unroll
            for (int cb = 0; cb < 4; cb++) {
                bf16x8 vf = *(const bf16x8*)(Vbase + (size_t)(cb * 16 + c) * LQ + j0 + s * 32 + q4 * 8);
                O[cb] = MFMA16(pf, vf, O[cb]);
            }
        }
    }
    #pragma unroll
    for (int r = 0; r < 4; r++) {
        int i = i0 + q4 * 4 + r;
        float inv = 1.0f / l_r[r];
        #pragma unroll
        for (int cb = 0; cb < 4; cb++) {
            int col = hh * 64 + cb * 16 + c;
            size_t oidx = ((size_t)i * BZ + b) * D + col;
            out[oidx] = O[cb][r] * inv + query[oidx];
        }
    }
}

// ---------------------------------------------------------------------------
extern "C" void kernel_launch(void* const* d_in, const int* in_sizes, int n_in,
                              void* d_out, int out_size, void* d_ws, size_t ws_size,
                              hipStream_t stream) {
    const float* query    = (const float*)d_in[0];
    const float* segments = (const float*)d_in[1];
    const float* Wq = (const float*)d_in[2];
    const float* bq = (const float*)d_in[3];
    const float* Wk = (const float*)d_in[4];
    const float* bk = (const float*)d_in[5];
    const float* Wv = (const float*)d_in[6];
    const float* bv = (const float*)d_in[7];
    float* out = (float*)d_out;

    const size_t NTOK = (size_t)BZ * LQ;
    char* ws = (char*)d_ws;
    unsigned short* hbuf  = (unsigned short*)ws;   ws += NTOK * D * 2;          // 8 MB
    unsigned short* Qb    = (unsigned short*)ws;   ws += NTOK * D * 2;          // 8 MB
    unsigned short* Kb    = (unsigned short*)ws;   ws += NTOK * D * 2;          // 8 MB
    unsigned short* Vt    = (unsigned short*)ws;   ws += NTOK * D * 2;          // 8 MB
    unsigned short* Wb    = (unsigned short*)ws;   ws += (size_t)3 * D * D * 2; // 1.5 MB
    float*          rnorm = (float*)ws;            ws += NTOK * 4;              // 32 KB
    unsigned char*  mask  = (unsigned char*)ws;    ws += (size_t)BZ * LQ * LQ;  // 8 MB
    unsigned char*  summ  = (unsigned char*)ws;    ws += 8192;                  // 8 KB
    int*            fix_cnt = (int*)ws;            ws += 64;
    unsigned int*   fix_list = (unsigned int*)ws;  /* 64 KB */

    hipMemsetAsync(fix_cnt, 0, 64, stream);
    prep_kernel<<<2816, 256, 0, stream>>>(query, Wq, Wk, Wv, hbuf, Wb, rnorm);
    gemm_kernel<<<1056, 256, 0, stream>>>(hbuf, Wb, rnorm, segments, bq, bk, bv,
                                          mask, summ, fix_cnt, fix_list, Qb, Kb, Vt);
    fixup_kernel<<<64, 64, 0, stream>>>(query, rnorm, segments, fix_cnt, fix_list, mask, summ);
    attn_kernel<<<dim3(LQ / 64, NH, BZ), 256, 0, stream>>>(Qb, Kb, Vt, mask, summ, query, out);
}

// Round 8
// 159.163 us; speedup vs baseline: 1.0082x; 1.0064x over previous
//
#include <hip/hip_runtime.h>
#include <math.h>

#define LQ 1024
#define BZ 8
#define D  512
#define NH 8
#define DH 64
#define IOU_THR 0.2f
#define COS_THR 0.2f
#define NEG (-1e30f)
#define FIXCAP 16384

typedef short bf16x8 __attribute__((ext_vector_type(8)));
typedef float f32x4  __attribute__((ext_vector_type(4)));

#define MFMA16(a, b, cacc) __builtin_amdgcn_mfma_f32_16x16x32_bf16(a, b, cacc, 0, 0, 0)

__device__ inline unsigned short f2bf(float x) {
    union { float f; unsigned int u; } v; v.f = x;
    unsigned int r = v.u + 0x7FFF + ((v.u >> 16) & 1);
    return (unsigned short)(r >> 16);
}

// ---------------------------------------------------------------------------
// Kernel 1: prep (query -> hi bf16, rnorm) + Wq/Wk/Wv -> bf16, fused.
// ---------------------------------------------------------------------------
__global__ __launch_bounds__(256) void prep_kernel(const float* __restrict__ query,
                                                   const float* __restrict__ Wq,
                                                   const float* __restrict__ Wk,
                                                   const float* __restrict__ Wv,
                                                   unsigned short* __restrict__ hi,
                                                   unsigned short* __restrict__ Wb,
                                                   float* __restrict__ rnorm) {
    int blk = blockIdx.x, tid = threadIdx.x;
    if (blk < 2048) {
        int w = tid >> 6, lane = tid & 63;
        int row = blk * 4 + w;                  // = b*LQ + i
        int b = row >> 10, i = row & 1023;
        const float* src = query + ((size_t)i * BZ + b) * D + lane * 8;
        float4 v0 = *(const float4*)src;
        float4 v1 = *(const float4*)(src + 4);
        uint4 pk;
        pk.x = (unsigned)f2bf(v0.x) | ((unsigned)f2bf(v0.y) << 16);
        pk.y = (unsigned)f2bf(v0.z) | ((unsigned)f2bf(v0.w) << 16);
        pk.z = (unsigned)f2bf(v1.x) | ((unsigned)f2bf(v1.y) << 16);
        pk.w = (unsigned)f2bf(v1.z) | ((unsigned)f2bf(v1.w) << 16);
        *(uint4*)(hi + (size_t)row * D + lane * 8) = pk;
        float ss = v0.x * v0.x + v0.y * v0.y + v0.z * v0.z + v0.w * v0.w
                 + v1.x * v1.x + v1.y * v1.y + v1.z * v1.z + v1.w * v1.w;
        #pragma unroll
        for (int s = 1; s < 64; s <<= 1) ss += __shfl_xor(ss, s);
        if (lane == 0) rnorm[row] = 1.0f / fmaxf(sqrtf(ss), 1e-8f);
    } else {
        int t = (blk - 2048) * 256 + tid;
        int mat = t >> 16;
        int off = (t & 65535) * 4;
        const float* src = (mat == 0) ? Wq : (mat == 1) ? Wk : Wv;
        float4 v = *(const float4*)(src + off);
        uint2 p;
        p.x = (unsigned)f2bf(v.x) | ((unsigned)f2bf(v.y) << 16);
        p.y = (unsigned)f2bf(v.z) | ((unsigned)f2bf(v.w) << 16);
        *(uint2*)(Wb + (size_t)mat * D * D + off) = p;
    }
}

// ---------------------------------------------------------------------------
// Kernel 2: fused QKV + symmetric mask GEMMs, register-prefetch ping-pong
// pipeline (one barrier/iter, no vmcnt drain). BK=32, 16 iters, 4 blocks/CU.
// Blocks 0..767: QKV. Blocks 768..1055: mask upper-tri tiles (writes both
// (i,j) and transposed tile + summaries).
// ---------------------------------------------------------------------------
__global__ __launch_bounds__(256) void gemm_kernel(const unsigned short* __restrict__ hi,
                                                   const unsigned short* __restrict__ Wb,
                                                   const float* __restrict__ rnorm,
                                                   const float* __restrict__ segments,
                                                   const float* __restrict__ bq,
                                                   const float* __restrict__ bk,
                                                   const float* __restrict__ bv,
                                                   unsigned char* __restrict__ mask,
                                                   unsigned char* __restrict__ summ,
                                                   int* __restrict__ fix_cnt,
                                                   unsigned int* __restrict__ fix_list,
                                                   unsigned short* __restrict__ Qb,
                                                   unsigned short* __restrict__ Kb,
                                                   unsigned short* __restrict__ Vt) {
    __shared__ short As[2][128 * 32], Bs[2][128 * 32];   // 2 x (8KB+8KB) ping-pong
    __shared__ float4 iSE[128], jSE[128];
    __shared__ int summ_lds[8][2], summ_t_lds[8][2];
    int blk = blockIdx.x, tid = threadIdx.x, w = tid >> 6, lane = tid & 63;
    int c = lane & 15, q4 = lane >> 4;
    int wr = w >> 1, wc = w & 1;

    bool is_qkv = blk < 768;
    const char *Asrc, *Bsrc;
    int b = 0, i0 = 0, j0 = 0, z = 0, m0 = 0, n0 = 0;
    if (is_qkv) {
        z = blk >> 8; int rem = blk & 255;
        m0 = (rem >> 2) * 128; n0 = (rem & 3) * 128;
        Asrc = (const char*)(hi + (size_t)m0 * D);
        Bsrc = (const char*)(Wb + (size_t)z * D * D + (size_t)n0 * D);
    } else {
        int id2 = blk - 768;           // 0..287
        b = id2 / 36;
        int t = id2 - b * 36;          // triangular index, it<=jt over 8x8
        int it = 0;
        while (t >= 8 - it) { t -= 8 - it; it++; }
        int jt = it + t;
        i0 = it * 128; j0 = jt * 128;
        Asrc = (const char*)(hi + ((size_t)b * LQ + i0) * D);
        Bsrc = (const char*)(hi + ((size_t)b * LQ + j0) * D);
        if (tid < 16) {
            summ_lds[tid >> 1][tid & 1] = 0;
            summ_t_lds[tid >> 1][tid & 1] = 0;
        }
    }

    // staging geometry (BK=32): per array 8 chunks of 1KB (16 rows x 64B).
    // wave w stages chunks n = 2w+m. lane L -> row 16n+(L>>2), physical 16B
    // slot L&3 holding logical k-group gl = (L&3)^((L>>3)&3). Read side uses
    // g_phys = q4 ^ ((c>>1)&3) -> <=2-way bank aliasing (free).
    int lrow = lane >> 2;                         // 0..15
    int gl   = (lane & 3) ^ ((lane >> 3) & 3);
    size_t goff = (size_t)lrow * 1024 + (size_t)gl * 16;   // within chunk 0
    int lds_off = lrow * 64 + (lane & 3) * 16;             // bytes within chunk

    uint4 ra[2], rb[2];
    // prologue: load k=0, stage into buf 0
    #pragma unroll
    for (int m = 0; m < 2; m++) {
        int n = 2 * w + m;
        ra[m] = *(const uint4*)(Asrc + (size_t)n * 16384 + goff);
        rb[m] = *(const uint4*)(Bsrc + (size_t)n * 16384 + goff);
    }
    #pragma unroll
    for (int m = 0; m < 2; m++) {
        int n = 2 * w + m;
        *(uint4*)((char*)As[0] + n * 1024 + lds_off) = ra[m];
        *(uint4*)((char*)Bs[0] + n * 1024 + lds_off) = rb[m];
    }
    __syncthreads();

    f32x4 acc[4][4] = {};
    int rswz = (c >> 1) & 3;
    for (int k = 0; k < 16; k++) {
        int cur = k & 1;
        if (k < 15) {
            size_t kb = (size_t)(k + 1) * 64;
            #pragma unroll
            for (int m = 0; m < 2; m++) {
                int n = 2 * w + m;
                ra[m] = *(const uint4*)(Asrc + kb + (size_t)n * 16384 + goff);
                rb[m] = *(const uint4*)(Bsrc + kb + (size_t)n * 16384 + goff);
            }
        }
        bf16x8 af[4], bf[4];
        #pragma unroll
        for (int f = 0; f < 4; f++) {
            af[f] = *(const bf16x8*)&As[cur][(wr * 64 + f * 16 + c) * 32 + (q4 ^ rswz) * 8];
            bf[f] = *(const bf16x8*)&Bs[cur][(wc * 64 + f * 16 + c) * 32 + (q4 ^ rswz) * 8];
        }
        #pragma unroll
        for (int fr = 0; fr < 4; fr++)
            #pragma unroll
            for (int fc = 0; fc < 4; fc++)
                acc[fr][fc] = MFMA16(af[fr], bf[fc], acc[fr][fc]);
        if (k < 15) {
            int nxt = cur ^ 1;
            #pragma unroll
            for (int m = 0; m < 2; m++) {
                int n = 2 * w + m;
                *(uint4*)((char*)As[nxt] + n * 1024 + lds_off) = ra[m];
                *(uint4*)((char*)Bs[nxt] + n * 1024 + lds_off) = rb[m];
            }
        }
        __syncthreads();
    }

    if (is_qkv) {
        const float* bias = (z == 0) ? bq : (z == 1) ? bk : bv;
        #pragma unroll
        for (int fr = 0; fr < 4; fr++)
            #pragma unroll
            for (int r = 0; r < 4; r++) {
                int m = m0 + wr * 64 + fr * 16 + q4 * 4 + r;
                int bb = m >> 10, i = m & 1023;
                #pragma unroll
                for (int fc = 0; fc < 4; fc++) {
                    int n = n0 + wc * 64 + fc * 16 + c;
                    unsigned short us = f2bf(acc[fr][fc][r] + bias[n]);
                    int hh = n >> 6, dh = n & 63;
                    size_t bh = (size_t)bb * NH + hh;
                    if (z == 2)
                        Vt[(bh * DH + dh) * LQ + i] = us;
                    else {
                        unsigned short* dst = (z == 0) ? Qb : Kb;
                        dst[(bh * LQ + i) * DH + dh] = us;
                    }
                }
            }
    } else {
        // stage segment geometry + rnorm (coalesced, once per block)
        const float2* seg2 = (const float2*)(segments + (size_t)b * LQ * 2);
        const float* rn = rnorm + b * LQ;
        if (tid < 128) {
            float2 cl = seg2[i0 + tid];
            iSE[tid] = make_float4(cl.x - cl.y * 0.5f, cl.x + cl.y * 0.5f, cl.y, rn[i0 + tid]);
        } else {
            float2 cl = seg2[j0 + tid - 128];
            jSE[tid - 128] = make_float4(cl.x - cl.y * 0.5f, cl.x + cl.y * 0.5f, cl.y, rn[j0 + tid - 128]);
        }
        __syncthreads();

        bool offdiag = (i0 != j0);
        unsigned char* mbase = mask + ((size_t)b << 20);
        int anyT[4] = {0, 0, 0, 0};    // transposed summary, per fc
        #pragma unroll
        for (int fr = 0; fr < 4; fr++) {
            int anyun = 0;
            unsigned int tpack[4] = {0, 0, 0, 0};   // transposed bytes, packed over r
            #pragma unroll
            for (int r = 0; r < 4; r++) {
                int il = wr * 64 + fr * 16 + q4 * 4 + r;
                int i = i0 + il;
                float4 I = iSE[il];
                #pragma unroll
                for (int fc = 0; fc < 4; fc++) {
                    int jl = wc * 64 + fc * 16 + c;
                    int j = j0 + jl;
                    float4 J = jSE[jl];
                    float cosv = acc[fr][fc][r] * I.w * J.w;
                    if (fabsf(cosv - COS_THR) < 1.5e-3f) {     // defer exact recompute
                        int idx = atomicAdd(fix_cnt, 1);
                        if (idx < FIXCAP)
                            fix_list[idx] = ((unsigned int)b << 20) | ((unsigned int)i << 10) | j;
                    }
                    float inter = fmaxf(fminf(I.y, J.y) - fmaxf(I.x, J.x), 0.0f);
                    float uni   = I.z + J.z - inter;
                    float iou   = inter / uni;
                    bool adj = ((iou <= IOU_THR) || (i == j)) && (cosv > COS_THR);
                    mbase[(size_t)i * LQ + j] = adj ? 0 : 1;   // 1 = masked
                    tpack[fc] |= (adj ? 0u : 1u) << (8 * r);
                    anyun |= adj ? 1 : 0;
                    anyT[fc] |= adj ? 1 : 0;
                }
            }
            if (anyun) atomicOr(&summ_lds[wr * 4 + fr][wc], 1);
            if (offdiag) {
                int ibase = i0 + wr * 64 + fr * 16 + q4 * 4;   // 4-aligned
                #pragma unroll
                for (int fc = 0; fc < 4; fc++) {
                    int j = j0 + wc * 64 + fc * 16 + c;
                    *(unsigned int*)&mbase[(size_t)j * LQ + ibase] = tpack[fc];
                }
            }
        }
        if (offdiag) {
            #pragma unroll
            for (int fc = 0; fc < 4; fc++)
                if (anyT[fc]) atomicOr(&summ_t_lds[wc * 4 + fc][wr], 1);
        }
        __syncthreads();
        if (tid < 16) {
            int lit = tid >> 1, ljt = tid & 1;
            summ[((size_t)b * 64 + (i0 >> 4) + lit) * 16 + (j0 >> 6) + ljt] =
                summ_lds[lit][ljt] ? 1 : 0;
            if (offdiag)
                summ[((size_t)b * 64 + (j0 >> 4) + lit) * 16 + (i0 >> 6) + ljt] =
                    summ_t_lds[lit][ljt] ? 1 : 0;
        }
    }
}

// ---------------------------------------------------------------------------
// Kernel 3: fixup — one wave per flagged element; cooperative fp64 dot over
// query rows. Patches BOTH (i,j) and (j,i). Stale summ=1 is safe.
// ---------------------------------------------------------------------------
__global__ __launch_bounds__(64) void fixup_kernel(const float* __restrict__ query,
                                                   const float* __restrict__ rnorm,
                                                   const float* __restrict__ segments,
                                                   const int* __restrict__ fix_cnt,
                                                   const unsigned int* __restrict__ fix_list,
                                                   unsigned char* __restrict__ mask,
                                                   unsigned char* __restrict__ summ) {
    int cnt = *fix_cnt; if (cnt > FIXCAP) cnt = FIXCAP;
    int lane = threadIdx.x;
    for (int e = blockIdx.x; e < cnt; e += gridDim.x) {
        unsigned int pk = fix_list[e];
        int b = pk >> 20, i = (pk >> 10) & 1023, j = pk & 1023;
        const float* hri = query + ((size_t)i * BZ + b) * D;
        const float* hrj = query + ((size_t)j * BZ + b) * D;
        double dd = 0.0;
        #pragma unroll
        for (int k = 0; k < D / 64; k++)
            dd += (double)hri[k * 64 + lane] * (double)hrj[k * 64 + lane];
        #pragma unroll
        for (int s = 1; s < 64; s <<= 1) dd += __shfl_xor(dd, s);
        if (lane == 0) {
            float rni = rnorm[b * LQ + i], rnj = rnorm[b * LQ + j];
            float cosv = (float)(dd * (double)rni * (double)rnj);
            const float* seg = segments + (size_t)b * LQ * 2;
            float ci = seg[i * 2], li = seg[i * 2 + 1];
            float cj = seg[j * 2], lj = seg[j * 2 + 1];
            float si = ci - li * 0.5f, ei = ci + li * 0.5f;
            float sj = cj - lj * 0.5f, ej = cj + lj * 0.5f;
            float inter = fmaxf(fminf(ei, ej) - fmaxf(si, sj), 0.0f);
            float iou = inter / (li + lj - inter);
            bool adj = ((iou <= IOU_THR) || (i == j)) && (cosv > COS_THR);
            unsigned char mv = adj ? 0 : 1;
            mask[((size_t)b * LQ + i) * LQ + j] = mv;
            mask[((size_t)b * LQ + j) * LQ + i] = mv;
            if (adj) {
                summ[((size_t)b * 64 + (i >> 4)) * 16 + (j >> 6)] = 1;
                summ[((size_t)b * 64 + (j >> 4)) * 16 + (i >> 6)] = 1;
            }
        }
    }
}

// ---------------------------------------------------------------------------
// Kernel 4: flash MFMA attention, summary-driven tile skipping; residual read
// directly from query (out[i][b][col] = O/l + query[i][b][col]).
// ---------------------------------------------------------------------------
__global__ __launch_bounds__(256) void attn_kernel(const unsigned short* __restrict__ Qb,
                                                   const unsigned short* __restrict__ Kb,
                                                   const unsigned short* __restrict__ Vt,
                                                   const unsigned char* __restrict__ mask,
                                                   const unsigned char* __restrict__ summ,
                                                   const float* __restrict__ query,
                                                   float* __restrict__ out) {
    int tid = threadIdx.x;
    int w = tid >> 6, lane = tid & 63;
    int c = lane & 15, q4 = lane >> 4;
    int hh = blockIdx.y, b = blockIdx.z;
    int i0 = blockIdx.x * 64 + w * 16;
    size_t bh = (size_t)b * NH + hh;

    __shared__ unsigned short p_lds[4][16][72];

    const unsigned short* Qrow = Qb + (bh * LQ + i0 + c) * DH;
    bf16x8 qa0 = *(const bf16x8*)(Qrow + q4 * 8);
    bf16x8 qa1 = *(const bf16x8*)(Qrow + 32 + q4 * 8);

    f32x4 O[4] = {};
    float m_r[4] = {NEG, NEG, NEG, NEG};
    float l_r[4] = {0.f, 0.f, 0.f, 0.f};

    const unsigned short* Kbase = Kb + bh * LQ * DH;
    const unsigned short* Vbase = Vt + bh * DH * LQ;
    const unsigned char*  mbase = mask + ((size_t)b * LQ + i0) * LQ;
    const unsigned char*  srow  = summ + ((size_t)b * 64 + (i0 >> 4)) * 16;

    for (int jt = 0; jt < 16; jt++) {
        if (!srow[jt]) continue;           // fully-masked tile: contributes nothing
        int j0 = jt * 64;
        f32x4 S[4] = {};
        #pragma unroll
        for (int cb = 0; cb < 4; cb++) {
            const unsigned short* krow = Kbase + (size_t)(j0 + cb * 16 + c) * DH;
            bf16x8 kf0 = *(const bf16x8*)(krow + q4 * 8);
            bf16x8 kf1 = *(const bf16x8*)(krow + 32 + q4 * 8);
            S[cb] = MFMA16(qa0, kf0, S[cb]);
            S[cb] = MFMA16(qa1, kf1, S[cb]);
        }
        float p[4][4];
        float tmax[4] = {NEG, NEG, NEG, NEG};
        #pragma unroll
        for (int cb = 0; cb < 4; cb++)
            #pragma unroll
            for (int r = 0; r < 4; r++) {
                float sc = S[cb][r] * 0.125f;
                unsigned char mm = mbase[(size_t)(q4 * 4 + r) * LQ + j0 + cb * 16 + c];
                sc = mm ? NEG : sc;
                p[cb][r] = sc;
                tmax[r] = fmaxf(tmax[r], sc);
            }
        #pragma unroll
        for (int r = 0; r < 4; r++) {
            float v = tmax[r];
            v = fmaxf(v, __shfl_xor(v, 1));
            v = fmaxf(v, __shfl_xor(v, 2));
            v = fmaxf(v, __shfl_xor(v, 4));
            v = fmaxf(v, __shfl_xor(v, 8));
            tmax[r] = v;
        }
        float rsum[4];
        #pragma unroll
        for (int r = 0; r < 4; r++) {
            float mn = fmaxf(m_r[r], tmax[r]);
            float alpha = __expf(m_r[r] - mn);
            m_r[r] = mn;
            l_r[r] *= alpha;
            #pragma unroll
            for (int cb2 = 0; cb2 < 4; cb2++) O[cb2][r] *= alpha;
            float s0 = 0.f;
            #pragma unroll
            for (int cb = 0; cb < 4; cb++) {
                float e = __expf(p[cb][r] - mn);
                p[cb][r] = e;
                s0 += e;
            }
            rsum[r] = s0;
        }
        #pragma unroll
        for (int r = 0; r < 4; r++) {
            float v = rsum[r];
            v += __shfl_xor(v, 1);
            v += __shfl_xor(v, 2);
            v += __shfl_xor(v, 4);
            v += __shfl_xor(v, 8);
            l_r[r] += v;
        }
        #pragma unroll
        for (int cb = 0; cb < 4; cb++)
            #pragma unroll
            for (int r = 0; r < 4; r++)
                p_lds[w][q4 * 4 + r][cb * 16 + c] = f2bf(p[cb][r]);
        // per-wave LDS: wave-internal lgkmcnt ordering suffices, no barrier
        #pragma unroll
        for (int s = 0; s < 2; s++) {
            bf16x8 pf = *(const bf16x8*)&p_lds[w][c][s * 32 + q4 * 8];
            #pragma unroll
            for (int cb = 0; cb < 4; cb++) {
                bf16x8 vf = *(const bf16x8*)(Vbase + (size_t)(cb * 16 + c) * LQ + j0 + s * 32 + q4 * 8);
                O[cb] = MFMA16(pf, vf, O[cb]);
            }
        }
    }
    #pragma unroll
    for (int r = 0; r < 4; r++) {
        int i = i0 + q4 * 4 + r;
        float inv = 1.0f / l_r[r];
        #pragma unroll
        for (int cb = 0; cb < 4; cb++) {
            int col = hh * 64 + cb * 16 + c;
            size_t oidx = ((size_t)i * BZ + b) * D + col;
            out[oidx] = O[cb][r] * inv + query[oidx];
        }
    }
}

// ---------------------------------------------------------------------------
extern "C" void kernel_launch(void* const* d_in, const int* in_sizes, int n_in,
                              void* d_out, int out_size, void* d_ws, size_t ws_size,
                              hipStream_t stream) {
    const float* query    = (const float*)d_in[0];
    const float* segments = (const float*)d_in[1];
    const float* Wq = (const float*)d_in[2];
    const float* bq = (const float*)d_in[3];
    const float* Wk = (const float*)d_in[4];
    const float* bk = (const float*)d_in[5];
    const float* Wv = (const float*)d_in[6];
    const float* bv = (const float*)d_in[7];
    float* out = (float*)d_out;

    const size_t NTOK = (size_t)BZ * LQ;
    char* ws = (char*)d_ws;
    unsigned short* hbuf  = (unsigned short*)ws;   ws += NTOK * D * 2;          // 8 MB
    unsigned short* Qb    = (unsigned short*)ws;   ws += NTOK * D * 2;          // 8 MB
    unsigned short* Kb    = (unsigned short*)ws;   ws += NTOK * D * 2;          // 8 MB
    unsigned short* Vt    = (unsigned short*)ws;   ws += NTOK * D * 2;          // 8 MB
    unsigned short* Wb    = (unsigned short*)ws;   ws += (size_t)3 * D * D * 2; // 1.5 MB
    float*          rnorm = (float*)ws;            ws += NTOK * 4;              // 32 KB
    unsigned char*  mask  = (unsigned char*)ws;    ws += (size_t)BZ * LQ * LQ;  // 8 MB
    unsigned char*  summ  = (unsigned char*)ws;    ws += 8192;                  // 8 KB
    int*            fix_cnt = (int*)ws;            ws += 64;
    unsigned int*   fix_list = (unsigned int*)ws;  /* 64 KB */

    hipMemsetAsync(fix_cnt, 0, 64, stream);
    prep_kernel<<<2816, 256, 0, stream>>>(query, Wq, Wk, Wv, hbuf, Wb, rnorm);
    gemm_kernel<<<1056, 256, 0, stream>>>(hbuf, Wb, rnorm, segments, bq, bk, bv,
                                          mask, summ, fix_cnt, fix_list, Qb, Kb, Vt);
    fixup_kernel<<<64, 64, 0, stream>>>(query, rnorm, segments, fix_cnt, fix_list, mask, summ);
    attn_kernel<<<dim3(LQ / 64, NH, BZ), 256, 0, stream>>>(Qb, Kb, Vt, mask, summ, query, out);
}

// Round 9
// 150.065 us; speedup vs baseline: 1.0693x; 1.0606x over previous
//
#include <hip/hip_runtime.h>
#include <math.h>

#define LQ 1024
#define BZ 8
#define D  512
#define NH 8
#define DH 64
#define IOU_THR 0.2f
#define COS_THR 0.2f
#define NEG (-1e30f)
#define FIXCAP 16384

typedef short bf16x8 __attribute__((ext_vector_type(8)));
typedef float f32x4  __attribute__((ext_vector_type(4)));

#define MFMA16(a, b, cacc) __builtin_amdgcn_mfma_f32_16x16x32_bf16(a, b, cacc, 0, 0, 0)

__device__ inline unsigned short f2bf(float x) {
    union { float f; unsigned int u; } v; v.f = x;
    unsigned int r = v.u + 0x7FFF + ((v.u >> 16) & 1);
    return (unsigned short)(r >> 16);
}

// ---------------------------------------------------------------------------
// Kernel 1: prep (query -> hi bf16, rnorm) + Wq/Wk/Wv -> bf16, fused.
// ---------------------------------------------------------------------------
__global__ __launch_bounds__(256) void prep_kernel(const float* __restrict__ query,
                                                   const float* __restrict__ Wq,
                                                   const float* __restrict__ Wk,
                                                   const float* __restrict__ Wv,
                                                   unsigned short* __restrict__ hi,
                                                   unsigned short* __restrict__ Wb,
                                                   float* __restrict__ rnorm) {
    int blk = blockIdx.x, tid = threadIdx.x;
    if (blk < 2048) {
        int w = tid >> 6, lane = tid & 63;
        int row = blk * 4 + w;                  // = b*LQ + i
        int b = row >> 10, i = row & 1023;
        const float* src = query + ((size_t)i * BZ + b) * D + lane * 8;
        float4 v0 = *(const float4*)src;
        float4 v1 = *(const float4*)(src + 4);
        uint4 pk;
        pk.x = (unsigned)f2bf(v0.x) | ((unsigned)f2bf(v0.y) << 16);
        pk.y = (unsigned)f2bf(v0.z) | ((unsigned)f2bf(v0.w) << 16);
        pk.z = (unsigned)f2bf(v1.x) | ((unsigned)f2bf(v1.y) << 16);
        pk.w = (unsigned)f2bf(v1.z) | ((unsigned)f2bf(v1.w) << 16);
        *(uint4*)(hi + (size_t)row * D + lane * 8) = pk;
        float ss = v0.x * v0.x + v0.y * v0.y + v0.z * v0.z + v0.w * v0.w
                 + v1.x * v1.x + v1.y * v1.y + v1.z * v1.z + v1.w * v1.w;
        #pragma unroll
        for (int s = 1; s < 64; s <<= 1) ss += __shfl_xor(ss, s);
        if (lane == 0) rnorm[row] = 1.0f / fmaxf(sqrtf(ss), 1e-8f);
    } else {
        int t = (blk - 2048) * 256 + tid;
        int mat = t >> 16;
        int off = (t & 65535) * 4;
        const float* src = (mat == 0) ? Wq : (mat == 1) ? Wk : Wv;
        float4 v = *(const float4*)(src + off);
        uint2 p;
        p.x = (unsigned)f2bf(v.x) | ((unsigned)f2bf(v.y) << 16);
        p.y = (unsigned)f2bf(v.z) | ((unsigned)f2bf(v.w) << 16);
        *(uint2*)(Wb + (size_t)mat * D * D + off) = p;
    }
}

// ---------------------------------------------------------------------------
// Kernel 2: fused QKV + symmetric mask GEMMs; reg-prefetch ping-pong K-loop.
// XCD-aware block remap (blk%8 ~ XCD): QKV blocks sharing an A-tile (12 per
// m-group) pinned to one XCD; mask blocks pinned xcd=batch so each batch's
// 1MB hi window stays L2-resident. QKV epilogue stages C in LDS and writes
// Q/K/Vt with coalesced uint4 stores.
// ---------------------------------------------------------------------------
__global__ __launch_bounds__(256) void gemm_kernel(const unsigned short* __restrict__ hi,
                                                   const unsigned short* __restrict__ Wb,
                                                   const float* __restrict__ rnorm,
                                                   const float* __restrict__ segments,
                                                   const float* __restrict__ bq,
                                                   const float* __restrict__ bk,
                                                   const float* __restrict__ bv,
                                                   unsigned char* __restrict__ mask,
                                                   unsigned char* __restrict__ summ,
                                                   int* __restrict__ fix_cnt,
                                                   unsigned int* __restrict__ fix_list,
                                                   unsigned short* __restrict__ Qb,
                                                   unsigned short* __restrict__ Kb,
                                                   unsigned short* __restrict__ Vt) {
    // SMEM: K-loop ping-pong As0|As1|Bs0|Bs1 (4x8KB); epilogue reuses it as a
    // 128x128 C tile with skewed pitch: byte(row,col)=row*272+(row>>3)*16+col*2
    // (rows 16B-aligned, stride-8-row gathers bank-spread).
    __shared__ __align__(16) char SMEM[35072];
    __shared__ float4 iSE[128], jSE[128];
    __shared__ int summ_lds[8][2], summ_t_lds[8][2];
    short* const As0 = (short*)SMEM;
    short* const As1 = As0 + 4096;
    short* const Bs0 = As1 + 4096;
    short* const Bs1 = Bs0 + 4096;

    int blk = blockIdx.x, tid = threadIdx.x, w = tid >> 6, lane = tid & 63;
    int c = lane & 15, q4 = lane >> 4;
    int wr = w >> 1, wc = w & 1;

    bool is_qkv = blk < 768;
    const char *Asrc, *Bsrc;
    int b = 0, i0 = 0, j0 = 0, z = 0, m0 = 0, n0 = 0;
    if (is_qkv) {
        // g = m-group 0..63 pinned to XCD g%8; inner = z*4 + n-quarter
        int g = (blk & 7) + 8 * ((blk >> 3) / 12);
        int inner = (blk >> 3) % 12;
        z = inner >> 2;
        m0 = g * 128;
        n0 = (inner & 3) * 128;
        Asrc = (const char*)(hi + (size_t)m0 * D);
        Bsrc = (const char*)(Wb + (size_t)z * D * D + (size_t)n0 * D);
    } else {
        int x = blk - 768;             // xcd = b = x%8
        b = x & 7;
        int t = x >> 3;                // 0..35 triangular index, it<=jt
        int it = 0;
        while (t >= 8 - it) { t -= 8 - it; it++; }
        int jt = it + t;
        i0 = it * 128; j0 = jt * 128;
        Asrc = (const char*)(hi + ((size_t)b * LQ + i0) * D);
        Bsrc = (const char*)(hi + ((size_t)b * LQ + j0) * D);
        if (tid < 16) {
            summ_lds[tid >> 1][tid & 1] = 0;
            summ_t_lds[tid >> 1][tid & 1] = 0;
        }
    }

    // staging geometry (BK=32): 8 chunks of 1KB (16 rows x 64B) per array.
    // wave w stages chunks 2w,2w+1. lane L -> row 16n+(L>>2), phys 16B slot
    // L&3 holding logical k-group (L&3)^((L>>3)&3). Reads: q4 ^ ((c>>1)&3).
    int lrow = lane >> 2;
    int gl   = (lane & 3) ^ ((lane >> 3) & 3);
    size_t goff = (size_t)lrow * 1024 + (size_t)gl * 16;
    int lds_off = lrow * 64 + (lane & 3) * 16;

    uint4 ra[2], rb[2];
    #pragma unroll
    for (int m = 0; m < 2; m++) {
        int n = 2 * w + m;
        ra[m] = *(const uint4*)(Asrc + (size_t)n * 16384 + goff);
        rb[m] = *(const uint4*)(Bsrc + (size_t)n * 16384 + goff);
    }
    #pragma unroll
    for (int m = 0; m < 2; m++) {
        int n = 2 * w + m;
        *(uint4*)((char*)As0 + n * 1024 + lds_off) = ra[m];
        *(uint4*)((char*)Bs0 + n * 1024 + lds_off) = rb[m];
    }
    __syncthreads();

    f32x4 acc[4][4] = {};
    int rswz = (c >> 1) & 3;
    for (int k = 0; k < 16; k++) {
        short* Ac = (k & 1) ? As1 : As0;
        short* Bc = (k & 1) ? Bs1 : Bs0;
        if (k < 15) {
            size_t kb = (size_t)(k + 1) * 64;
            #pragma unroll
            for (int m = 0; m < 2; m++) {
                int n = 2 * w + m;
                ra[m] = *(const uint4*)(Asrc + kb + (size_t)n * 16384 + goff);
                rb[m] = *(const uint4*)(Bsrc + kb + (size_t)n * 16384 + goff);
            }
        }
        bf16x8 af[4], bf[4];
        #pragma unroll
        for (int f = 0; f < 4; f++) {
            af[f] = *(const bf16x8*)&Ac[(wr * 64 + f * 16 + c) * 32 + (q4 ^ rswz) * 8];
            bf[f] = *(const bf16x8*)&Bc[(wc * 64 + f * 16 + c) * 32 + (q4 ^ rswz) * 8];
        }
        #pragma unroll
        for (int fr = 0; fr < 4; fr++)
            #pragma unroll
            for (int fc = 0; fc < 4; fc++)
                acc[fr][fc] = MFMA16(af[fr], bf[fc], acc[fr][fc]);
        if (k < 15) {
            short* An = (k & 1) ? As0 : As1;
            short* Bn = (k & 1) ? Bs0 : Bs1;
            #pragma unroll
            for (int m = 0; m < 2; m++) {
                int n = 2 * w + m;
                *(uint4*)((char*)An + n * 1024 + lds_off) = ra[m];
                *(uint4*)((char*)Bn + n * 1024 + lds_off) = rb[m];
            }
        }
        __syncthreads();
    }

    if (is_qkv) {
        const float* bias = (z == 0) ? bq : (z == 1) ? bk : bv;
        // stage C tile (bf16, +bias) into skewed LDS
        #pragma unroll
        for (int fr = 0; fr < 4; fr++)
            #pragma unroll
            for (int r = 0; r < 4; r++) {
                int row = wr * 64 + fr * 16 + q4 * 4 + r;
                char* rbase = SMEM + row * 272 + (row >> 3) * 16;
                #pragma unroll
                for (int fc = 0; fc < 4; fc++) {
                    int col = wc * 64 + fc * 16 + c;
                    *(unsigned short*)(rbase + col * 2) =
                        f2bf(acc[fr][fc][r] + bias[n0 + col]);
                }
            }
        __syncthreads();
        int bb = m0 >> 10, ib = m0 & 1023;
        if (z < 2) {
            unsigned short* dst = (z == 0) ? Qb : Kb;
            #pragma unroll
            for (int it2 = 0; it2 < 8; it2++) {
                int idx = it2 * 256 + tid;
                int row = idx >> 4, cg = idx & 15;
                uint4 v = *(const uint4*)(SMEM + row * 272 + (row >> 3) * 16 + cg * 16);
                int n = n0 + cg * 8;
                int hh = n >> 6, dh = n & 63;
                *(uint4*)(dst + (((size_t)bb * NH + hh) * LQ + ib + row) * DH + dh) = v;
            }
        } else {
            #pragma unroll
            for (int it2 = 0; it2 < 8; it2++) {
                int idx = it2 * 256 + tid;
                int rowg = idx & 15, colI = idx >> 4;
                union { unsigned short s[8]; uint4 v; } u;
                char* gbase = SMEM + rowg * 16;   // (row>>3)*16 with row=rowg*8+rr
                #pragma unroll
                for (int rr = 0; rr < 8; rr++)
                    u.s[rr] = *(const unsigned short*)(gbase + (rowg * 8 + rr) * 272 + colI * 2);
                int n = n0 + colI;
                int hh = n >> 6, dh = n & 63;
                *(uint4*)(Vt + (((size_t)bb * NH + hh) * DH + dh) * LQ + ib + rowg * 8) = u.v;
            }
        }
    } else {
        // stage segment geometry + rnorm (coalesced, once per block)
        const float2* seg2 = (const float2*)(segments + (size_t)b * LQ * 2);
        const float* rn = rnorm + b * LQ;
        if (tid < 128) {
            float2 cl = seg2[i0 + tid];
            iSE[tid] = make_float4(cl.x - cl.y * 0.5f, cl.x + cl.y * 0.5f, cl.y, rn[i0 + tid]);
        } else {
            float2 cl = seg2[j0 + tid - 128];
            jSE[tid - 128] = make_float4(cl.x - cl.y * 0.5f, cl.x + cl.y * 0.5f, cl.y, rn[j0 + tid - 128]);
        }
        __syncthreads();

        bool offdiag = (i0 != j0);
        unsigned char* mbase = mask + ((size_t)b << 20);
        int anyT[4] = {0, 0, 0, 0};
        #pragma unroll
        for (int fr = 0; fr < 4; fr++) {
            int anyun = 0;
            unsigned int tpack[4] = {0, 0, 0, 0};
            #pragma unroll
            for (int r = 0; r < 4; r++) {
                int il = wr * 64 + fr * 16 + q4 * 4 + r;
                int i = i0 + il;
                float4 I = iSE[il];
                #pragma unroll
                for (int fc = 0; fc < 4; fc++) {
                    int jl = wc * 64 + fc * 16 + c;
                    int j = j0 + jl;
                    float4 J = jSE[jl];
                    float cosv = acc[fr][fc][r] * I.w * J.w;
                    if (fabsf(cosv - COS_THR) < 1.5e-3f) {
                        int idx = atomicAdd(fix_cnt, 1);
                        if (idx < FIXCAP)
                            fix_list[idx] = ((unsigned int)b << 20) | ((unsigned int)i << 10) | j;
                    }
                    float inter = fmaxf(fminf(I.y, J.y) - fmaxf(I.x, J.x), 0.0f);
                    float uni   = I.z + J.z - inter;
                    float iou   = inter / uni;
                    bool adj = ((iou <= IOU_THR) || (i == j)) && (cosv > COS_THR);
                    mbase[(size_t)i * LQ + j] = adj ? 0 : 1;
                    tpack[fc] |= (adj ? 0u : 1u) << (8 * r);
                    anyun |= adj ? 1 : 0;
                    anyT[fc] |= adj ? 1 : 0;
                }
            }
            if (anyun) atomicOr(&summ_lds[wr * 4 + fr][wc], 1);
            if (offdiag) {
                int ibase = i0 + wr * 64 + fr * 16 + q4 * 4;
                #pragma unroll
                for (int fc = 0; fc < 4; fc++) {
                    int j = j0 + wc * 64 + fc * 16 + c;
                    *(unsigned int*)&mbase[(size_t)j * LQ + ibase] = tpack[fc];
                }
            }
        }
        if (offdiag) {
            #pragma unroll
            for (int fc = 0; fc < 4; fc++)
                if (anyT[fc]) atomicOr(&summ_t_lds[wc * 4 + fc][wr], 1);
        }
        __syncthreads();
        if (tid < 16) {
            int lit = tid >> 1, ljt = tid & 1;
            summ[((size_t)b * 64 + (i0 >> 4) + lit) * 16 + (j0 >> 6) + ljt] =
                summ_lds[lit][ljt] ? 1 : 0;
            if (offdiag)
                summ[((size_t)b * 64 + (j0 >> 4) + lit) * 16 + (i0 >> 6) + ljt] =
                    summ_t_lds[lit][ljt] ? 1 : 0;
        }
    }
}

// ---------------------------------------------------------------------------
// Kernel 3: fixup — one wave per flagged element; cooperative fp64 dot over
// query rows. Patches BOTH (i,j) and (j,i). Stale summ=1 is safe.
// ---------------------------------------------------------------------------
__global__ __launch_bounds__(64) void fixup_kernel(const float* __restrict__ query,
                                                   const float* __restrict__ rnorm,
                                                   const float* __restrict__ segments,
                                                   const int* __restrict__ fix_cnt,
                                                   const unsigned int* __restrict__ fix_list,
                                                   unsigned char* __restrict__ mask,
                                                   unsigned char* __restrict__ summ) {
    int cnt = *fix_cnt; if (cnt > FIXCAP) cnt = FIXCAP;
    int lane = threadIdx.x;
    for (int e = blockIdx.x; e < cnt; e += gridDim.x) {
        unsigned int pk = fix_list[e];
        int b = pk >> 20, i = (pk >> 10) & 1023, j = pk & 1023;
        const float* hri = query + ((size_t)i * BZ + b) * D;
        const float* hrj = query + ((size_t)j * BZ + b) * D;
        double dd = 0.0;
        #pragma unroll
        for (int k = 0; k < D / 64; k++)
            dd += (double)hri[k * 64 + lane] * (double)hrj[k * 64 + lane];
        #pragma unroll
        for (int s = 1; s < 64; s <<= 1) dd += __shfl_xor(dd, s);
        if (lane == 0) {
            float rni = rnorm[b * LQ + i], rnj = rnorm[b * LQ + j];
            float cosv = (float)(dd * (double)rni * (double)rnj);
            const float* seg = segments + (size_t)b * LQ * 2;
            float ci = seg[i * 2], li = seg[i * 2 + 1];
            float cj = seg[j * 2], lj = seg[j * 2 + 1];
            float si = ci - li * 0.5f, ei = ci + li * 0.5f;
            float sj = cj - lj * 0.5f, ej = cj + lj * 0.5f;
            float inter = fmaxf(fminf(ei, ej) - fmaxf(si, sj), 0.0f);
            float iou = inter / (li + lj - inter);
            bool adj = ((iou <= IOU_THR) || (i == j)) && (cosv > COS_THR);
            unsigned char mv = adj ? 0 : 1;
            mask[((size_t)b * LQ + i) * LQ + j] = mv;
            mask[((size_t)b * LQ + j) * LQ + i] = mv;
            if (adj) {
                summ[((size_t)b * 64 + (i >> 4)) * 16 + (j >> 6)] = 1;
                summ[((size_t)b * 64 + (j >> 4)) * 16 + (i >> 6)] = 1;
            }
        }
    }
}

// ---------------------------------------------------------------------------
// Kernel 4: flash MFMA attention, summary-driven tile skipping; residual read
// directly from query (out[i][b][col] = O/l + query[i][b][col]).
// ---------------------------------------------------------------------------
__global__ __launch_bounds__(256) void attn_kernel(const unsigned short* __restrict__ Qb,
                                                   const unsigned short* __restrict__ Kb,
                                                   const unsigned short* __restrict__ Vt,
                                                   const unsigned char* __restrict__ mask,
                                                   const unsigned char* __restrict__ summ,
                                                   const float* __restrict__ query,
                                                   float* __restrict__ out) {
    int tid = threadIdx.x;
    int w = tid >> 6, lane = tid & 63;
    int c = lane & 15, q4 = lane >> 4;
    int hh = blockIdx.y, b = blockIdx.z;
    int i0 = blockIdx.x * 64 + w * 16;
    size_t bh = (size_t)b * NH + hh;

    __shared__ unsigned short p_lds[4][16][72];

    const unsigned short* Qrow = Qb + (bh * LQ + i0 + c) * DH;
    bf16x8 qa0 = *(const bf16x8*)(Qrow + q4 * 8);
    bf16x8 qa1 = *(const bf16x8*)(Qrow + 32 + q4 * 8);

    f32x4 O[4] = {};
    float m_r[4] = {NEG, NEG, NEG, NEG};
    float l_r[4] = {0.f, 0.f, 0.f, 0.f};

    const unsigned short* Kbase = Kb + bh * LQ * DH;
    const unsigned short* Vbase = Vt + bh * DH * LQ;
    const unsigned char*  mbase = mask + ((size_t)b * LQ + i0) * LQ;
    const unsigned char*  srow  = summ + ((size_t)b * 64 + (i0 >> 4)) * 16;

    for (int jt = 0; jt < 16; jt++) {
        if (!srow[jt]) continue;
        int j0 = jt * 64;
        f32x4 S[4] = {};
        #pragma unroll
        for (int cb = 0; cb < 4; cb++) {
            const unsigned short* krow = Kbase + (size_t)(j0 + cb * 16 + c) * DH;
            bf16x8 kf0 = *(const bf16x8*)(krow + q4 * 8);
            bf16x8 kf1 = *(const bf16x8*)(krow + 32 + q4 * 8);
            S[cb] = MFMA16(qa0, kf0, S[cb]);
            S[cb] = MFMA16(qa1, kf1, S[cb]);
        }
        float p[4][4];
        float tmax[4] = {NEG, NEG, NEG, NEG};
        #pragma unroll
        for (int cb = 0; cb < 4; cb++)
            #pragma unroll
            for (int r = 0; r < 4; r++) {
                float sc = S[cb][r] * 0.125f;
                unsigned char mm = mbase[(size_t)(q4 * 4 + r) * LQ + j0 + cb * 16 + c];
                sc = mm ? NEG : sc;
                p[cb][r] = sc;
                tmax[r] = fmaxf(tmax[r], sc);
            }
        #pragma unroll
        for (int r = 0; r < 4; r++) {
            float v = tmax[r];
            v = fmaxf(v, __shfl_xor(v, 1));
            v = fmaxf(v, __shfl_xor(v, 2));
            v = fmaxf(v, __shfl_xor(v, 4));
            v = fmaxf(v, __shfl_xor(v, 8));
            tmax[r] = v;
        }
        float rsum[4];
        #pragma unroll
        for (int r = 0; r < 4; r++) {
            float mn = fmaxf(m_r[r], tmax[r]);
            float alpha = __expf(m_r[r] - mn);
            m_r[r] = mn;
            l_r[r] *= alpha;
            #pragma unroll
            for (int cb2 = 0; cb2 < 4; cb2++) O[cb2][r] *= alpha;
            float s0 = 0.f;
            #pragma unroll
            for (int cb = 0; cb < 4; cb++) {
                float e = __expf(p[cb][r] - mn);
                p[cb][r] = e;
                s0 += e;
            }
            rsum[r] = s0;
        }
        #pragma unroll
        for (int r = 0; r < 4; r++) {
            float v = rsum[r];
            v += __shfl_xor(v, 1);
            v += __shfl_xor(v, 2);
            v += __shfl_xor(v, 4);
            v += __shfl_xor(v, 8);
            l_r[r] += v;
        }
        #pragma unroll
        for (int cb = 0; cb < 4; cb++)
            #pragma unroll
            for (int r = 0; r < 4; r++)
                p_lds[w][q4 * 4 + r][cb * 16 + c] = f2bf(p[cb][r]);
        #pragma unroll
        for (int s = 0; s < 2; s++) {
            bf16x8 pf = *(const bf16x8*)&p_lds[w][c][s * 32 + q4 * 8];
            #pragma unroll
            for (int cb = 0; cb < 4; cb++) {
                bf16x8 vf = *(const bf16x8*)(Vbase + (size_t)(cb * 16 + c) * LQ + j0 + s * 32 + q4 * 8);
                O[cb] = MFMA16(pf, vf, O[cb]);
            }
        }
    }
    #pragma unroll
    for (int r = 0; r < 4; r++) {
        int i = i0 + q4 * 4 + r;
        float inv = 1.0f / l_r[r];
        #pragma unroll
        for (int cb = 0; cb < 4; cb++) {
            int col = hh * 64 + cb * 16 + c;
            size_t oidx = ((size_t)i * BZ + b) * D + col;
            out[oidx] = O[cb][r] * inv + query[oidx];
        }
    }
}

// ---------------------------------------------------------------------------
extern "C" void kernel_launch(void* const* d_in, const int* in_sizes, int n_in,
                              void* d_out, int out_size, void* d_ws, size_t ws_size,
                              hipStream_t stream) {
    const float* query    = (const float*)d_in[0];
    const float* segments = (const float*)d_in[1];
    const float* Wq = (const float*)d_in[2];
    const float* bq = (const float*)d_in[3];
    const float* Wk = (const float*)d_in[4];
    const float* bk = (const float*)d_in[5];
    const float* Wv = (const float*)d_in[6];
    const float* bv = (const float*)d_in[7];
    float* out = (float*)d_out;

    const size_t NTOK = (size_t)BZ * LQ;
    char* ws = (char*)d_ws;
    unsigned short* hbuf  = (unsigned short*)ws;   ws += NTOK * D * 2;          // 8 MB
    unsigned short* Qb    = (unsigned short*)ws;   ws += NTOK * D * 2;          // 8 MB
    unsigned short* Kb    = (unsigned short*)ws;   ws += NTOK * D * 2;          // 8 MB
    unsigned short* Vt    = (unsigned short*)ws;   ws += NTOK * D * 2;          // 8 MB
    unsigned short* Wb    = (unsigned short*)ws;   ws += (size_t)3 * D * D * 2; // 1.5 MB
    float*          rnorm = (float*)ws;            ws += NTOK * 4;              // 32 KB
    unsigned char*  mask  = (unsigned char*)ws;    ws += (size_t)BZ * LQ * LQ;  // 8 MB
    unsigned char*  summ  = (unsigned char*)ws;    ws += 8192;                  // 8 KB
    int*            fix_cnt = (int*)ws;            ws += 64;
    unsigned int*   fix_list = (unsigned int*)ws;  /* 64 KB */

    hipMemsetAsync(fix_cnt, 0, 64, stream);
    prep_kernel<<<2816, 256, 0, stream>>>(query, Wq, Wk, Wv, hbuf, Wb, rnorm);
    gemm_kernel<<<1056, 256, 0, stream>>>(hbuf, Wb, rnorm, segments, bq, bk, bv,
                                          mask, summ, fix_cnt, fix_list, Qb, Kb, Vt);
    fixup_kernel<<<64, 64, 0, stream>>>(query, rnorm, segments, fix_cnt, fix_list, mask, summ);
    attn_kernel<<<dim3(LQ / 64, NH, BZ), 256, 0, stream>>>(Qb, Kb, Vt, mask, summ, query, out);
}